// Round 9
// baseline (1243.971 us; speedup 1.0000x reference)
//
#include <hip/hip_runtime.h>
#include <stdint.h>

typedef unsigned short u16;
typedef __attribute__((ext_vector_type(4))) float f32x4;
typedef __attribute__((ext_vector_type(8))) __bf16 bf16x8;
typedef __attribute__((ext_vector_type(8))) unsigned short u16x8;

__device__ __forceinline__ u16 f2bf(float f) {
  unsigned u = __builtin_bit_cast(unsigned, f);
  u = (u + 0x7fffu + ((u >> 16) & 1u)) >> 16;
  return (u16)u;
}

typedef __attribute__((address_space(1))) const void gvoid_t;
typedef __attribute__((address_space(3))) void lvoid_t;

__device__ __forceinline__ void gload_lds16(const void* g, void* l) {
  __builtin_amdgcn_global_load_lds((gvoid_t*)g, (lvoid_t*)l, 16, 0, 0);
}

// ---------------- dequant: w[row][k] = (q[row][k] - z[row][k/128]) * s[row][k/128], bf16
__global__ __launch_bounds__(256)
void dequant_kernel(const int* __restrict__ q, const float* __restrict__ s,
                    const int* __restrict__ z, u16* __restrict__ w, int K) {
  const int row = blockIdx.y;
  const int k = (blockIdx.x * 256 + threadIdx.x) << 3;
  const int ng = K >> 7;
  const int g = k >> 7;
  const float sv = s[(size_t)row * ng + g];
  const float zv = (float)z[(size_t)row * ng + g];
  const int4* qp = (const int4*)(q + (size_t)row * K + k);
  const int4 a = qp[0], b = qp[1];
  u16x8 o;
  o[0] = f2bf(((float)a.x - zv) * sv);
  o[1] = f2bf(((float)a.y - zv) * sv);
  o[2] = f2bf(((float)a.z - zv) * sv);
  o[3] = f2bf(((float)a.w - zv) * sv);
  o[4] = f2bf(((float)b.x - zv) * sv);
  o[5] = f2bf(((float)b.y - zv) * sv);
  o[6] = f2bf(((float)b.z - zv) * sv);
  o[7] = f2bf(((float)b.w - zv) * sv);
  *reinterpret_cast<u16x8*>(w + (size_t)row * K + k) = o;
}

// ---------------- fp32 -> bf16 bulk convert (x)
__global__ __launch_bounds__(256)
void cvt_kernel(const float* __restrict__ in, u16* __restrict__ out) {
  const size_t i = ((size_t)blockIdx.x * 256 + threadIdx.x) << 3;
  const float4* p = (const float4*)(in + i);
  const float4 a = p[0], b = p[1];
  u16x8 o;
  o[0] = f2bf(a.x); o[1] = f2bf(a.y); o[2] = f2bf(a.z); o[3] = f2bf(a.w);
  o[4] = f2bf(b.x); o[5] = f2bf(b.y); o[6] = f2bf(b.z); o[7] = f2bf(b.w);
  *reinterpret_cast<u16x8*>(out + i) = o;
}

// ---------------- 128x256 4-phase GEMM v7: C = A * B^T (bf16, K-major)
// 512 thr = 8 waves (2M x 4N); per-wave 64x64 out; BK=64; buf parity = K-tile parity.
// vs v6: BM 256->128. Grid: GEMM1 1792 = 7.0 exact CU-rounds (tail fix, was 3.5),
// GEMM2 512 = 2.0. LDS reads 384->256 b128/CU/iter (A-amplification on half-size A).
// LDS 96 KiB. Per K-tile: read ALL 16 frags in one phase; MFMA split ks0/ks1.
// Stage ledger (per-thread loads; A=2, B-half=2):
//   prologue: T0{A,Bh0,Bh1}=6, T1{A,Bh0}=4; gate vmcnt(4) -> T0 landed.
//   ph1: rd all buf0; stg B(T1)h1->buf1   | MFMA(a1,b1)          [outst 6]
//   ph2: stg A(T2),B(T2)h0->buf0          | MFMA(a3,b2); vmcnt(4) -> T1 landed [10->4]
//   ph3: rd all buf1; stg B(T2)h1->buf0   | MFMA(a1,b1)          [6]
//   ph4: stg A(T3),B(T3)h0->buf1          | MFMA(a3,b2); vmcnt(4) -> T2 landed [10->4]
// Region-safety: every stage targets a region whose reads drained (lgkm0+BAR) >=1
// barrier earlier. Counted vmcnt never 0 in loop (T4).
template<bool RELU2>
__global__ __launch_bounds__(512, 2)
void gemm128(const u16* __restrict__ Ap, const u16* __restrict__ Bp,
             void* __restrict__ Cptr, int M, int N, int K) {
  __shared__ __align__(16) u16 As[2][128][64];
  __shared__ __align__(16) u16 Bs[2][256][64];
  const int tid = threadIdx.x;
  const int lane = tid & 63;
  const int wid = tid >> 6;
  const int wr = wid >> 2, wc = wid & 3;   // wr 0..1 (64-row half), wc 0..3 (64-col quarter)

  const int nbx = N >> 8;
  const int nwg = gridDim.x;
  int bid = blockIdx.x;
  bid = (bid & 7) * (nwg >> 3) + (bid >> 3);   // XCD swizzle (nwg % 8 == 0)
  const int m0 = (bid / nbx) << 7;             // n-fastest (R6 order; BM=128)
  const int n0 = (bid % nbx) << 8;

  const int srow = tid >> 3;        // staging row within 64-row sweep
  const int scol = tid & 7;         // staging 16B segment
  const int lr = lane & 15;
  const int lk = (lane >> 4) << 3;
  const int xorc = (lr & 7) << 3;   // read-side swizzle (row&7 == lr&7)

  f32x4 acc[4][4] = {};
  bf16x8 a1[4], a3[4], b1[4], b2[4];

  const int nk = K >> 6;

#define STG_A(bufi, kt) do { _Pragma("unroll") \
  for (int l_ = 0; l_ < 2; ++l_) { \
    const int r_ = l_ * 64 + srow; \
    gload_lds16(Ap + (size_t)(m0 + r_) * K + (size_t)((kt) << 6) + ((scol ^ (srow & 7)) << 3), \
                &As[bufi][r_][scol << 3]); } } while (0)
#define STG_B(bufi, h, kt) do { _Pragma("unroll") \
  for (int l_ = 0; l_ < 2; ++l_) { \
    const int r_ = (h) * 128 + l_ * 64 + srow; \
    gload_lds16(Bp + (size_t)(n0 + r_) * K + (size_t)((kt) << 6) + ((scol ^ (srow & 7)) << 3), \
                &Bs[bufi][r_][scol << 3]); } } while (0)
#define RD_A(bufi, ks, dst) do { _Pragma("unroll") \
  for (int i_ = 0; i_ < 4; ++i_) { \
    const int row_ = wr * 64 + i_ * 16 + lr; \
    dst[i_] = *reinterpret_cast<const bf16x8*>(&As[bufi][row_][((ks) * 32 + lk) ^ xorc]); } } while (0)
#define RD_B(bufi, ks, dst) do { _Pragma("unroll") \
  for (int j_ = 0; j_ < 4; ++j_) { \
    const int row_ = wc * 64 + j_ * 16 + lr; \
    dst[j_] = *reinterpret_cast<const bf16x8*>(&Bs[bufi][row_][((ks) * 32 + lk) ^ xorc]); } } while (0)
#define MFMA16(ASET, BSET) do { _Pragma("unroll") \
  for (int i_ = 0; i_ < 4; ++i_) { _Pragma("unroll") \
    for (int j_ = 0; j_ < 4; ++j_) \
      acc[i_][j_] = __builtin_amdgcn_mfma_f32_16x16x32_bf16( \
        ASET[i_], BSET[j_], acc[i_][j_], 0, 0, 0); } } while (0)
#define BARO() do { asm volatile("" ::: "memory"); __builtin_amdgcn_s_barrier(); \
  asm volatile("" ::: "memory"); } while (0)
#define PH(GATEOP, Q) do { \
  BARO(); \
  asm volatile("s_waitcnt lgkmcnt(0)" ::: "memory"); \
  __builtin_amdgcn_sched_barrier(0); \
  __builtin_amdgcn_s_setprio(1); Q; __builtin_amdgcn_s_setprio(0); \
  GATEOP; \
  BARO(); \
} while (0)
#define NOGATE do {} while (0)
#define GATE4 asm volatile("s_waitcnt vmcnt(4)" ::: "memory")

  // prologue: T0 {A,Bh0,Bh1} then T1 {A,Bh0}; gate leaves T1's 4 in flight
  STG_A(0, 0); STG_B(0, 0, 0); STG_B(0, 1, 0);
  STG_A(1, 1); STG_B(1, 0, 1);
  asm volatile("s_waitcnt vmcnt(4)" ::: "memory");
  BARO();

  const int nit = nk >> 1;
  for (int it = 0; it < nit; ++it) {
    const int t1 = 2 * it + 1;
    int t2 = 2 * it + 2; if (t2 >= nk) t2 -= nk;   // wrap: tail stages are dummies
    int t3 = 2 * it + 3; if (t3 >= nk) t3 -= nk;
    // ph1: tile T0 (buf0) reads; finish T1's B
    RD_A(0, 0, a1); RD_A(0, 1, a3); RD_B(0, 0, b1); RD_B(0, 1, b2);
    STG_B(1, 1, t1);
    PH(NOGATE, MFMA16(a1, b1));
    // ph2: stage T2 A + B-h0; gate completes T1
    STG_A(0, t2); STG_B(0, 0, t2);
    PH(GATE4, MFMA16(a3, b2));
    // ph3: tile T1 (buf1) reads; finish T2's B
    RD_A(1, 0, a1); RD_A(1, 1, a3); RD_B(1, 0, b1); RD_B(1, 1, b2);
    STG_B(0, 1, t2);
    PH(NOGATE, MFMA16(a1, b1));
    // ph4: stage T3 A + B-h0; gate completes T2
    STG_A(1, t3); STG_B(1, 0, t3);
    PH(GATE4, MFMA16(a3, b2));
  }
  asm volatile("s_waitcnt vmcnt(0)" ::: "memory");  // drain dummy stages before epilogue

  // epilogue: C/D layout col = lane&15, row = (lane>>4)*4 + reg  [m89-verified]
  const int crow = (lane >> 4) << 2;
  const int ccol = lane & 15;
#pragma unroll
  for (int i = 0; i < 4; ++i) {
#pragma unroll
    for (int j = 0; j < 4; ++j) {
#pragma unroll
      for (int q = 0; q < 4; ++q) {
        const int m = m0 + wr * 64 + i * 16 + crow + q;
        const int n = n0 + wc * 64 + j * 16 + ccol;
        const float v = acc[i][j][q];
        if constexpr (RELU2) {
          const float r = fmaxf(v, 0.f);
          ((u16*)Cptr)[(size_t)m * N + n] = f2bf(r * r);
        } else {
          ((float*)Cptr)[(size_t)m * N + n] = v;
        }
      }
    }
  }
#undef STG_A
#undef STG_B
#undef RD_A
#undef RD_B
#undef MFMA16
#undef BARO
#undef PH
#undef NOGATE
#undef GATE4
}

extern "C" void kernel_launch(void* const* d_in, const int* in_sizes, int n_in,
                              void* d_out, int out_size, void* d_ws, size_t ws_size,
                              hipStream_t stream) {
  const float* x    = (const float*)d_in[0];
  const int*   q_up = (const int*)d_in[1];
  const float* s_up = (const float*)d_in[2];
  const int*   z_up = (const int*)d_in[3];
  const int*   q_dn = (const int*)d_in[4];
  const float* s_dn = (const float*)d_in[5];
  const int*   z_dn = (const int*)d_in[6];
  float* y = (float*)d_out;

  const int H = 4096, I = 14336;
  const int M = in_sizes[0] / H;  // 4096 tokens

  const size_t wbytes = (size_t)I * H * 2;   // 117.4 MB bf16 weight buffer (reused)
  const size_t abytes = (size_t)M * I * 2;   // 117.4 MB bf16 activations
  const size_t xbytes = (size_t)M * H * 2;   // 33.5 MB bf16 x
  u16* wbuf = (u16*)d_ws;
  u16* abuf = (u16*)((char*)d_ws + wbytes);
  u16* xbf  = (u16*)((char*)d_ws + wbytes + abytes);
  if (ws_size < wbytes + abytes + xbytes) return;  // insufficient scratch: fail cleanly

  // 1. dequant W_up [I, H] -> bf16
  dequant_kernel<<<dim3(H / 8 / 256, I), 256, 0, stream>>>(q_up, s_up, z_up, wbuf, H);
  // 1b. x -> bf16
  cvt_kernel<<<dim3((int)(((size_t)M * H) >> 11)), 256, 0, stream>>>(x, xbf);
  // 2. a = relu(x @ W_up^T)^2, bf16   (grid 1792 % 8 == 0; 7.0 CU-rounds)
  gemm128<true><<<dim3((M / 128) * (I / 256)), 512, 0, stream>>>(xbf, wbuf, abuf, M, I, H);
  // 3. dequant W_down [H, I] -> bf16
  dequant_kernel<<<dim3(I / 8 / 256, H), 256, 0, stream>>>(q_dn, s_dn, z_dn, wbuf, I);
  // 4. y = a @ W_down^T, fp32   (grid 512 % 8 == 0; 2.0 CU-rounds)
  gemm128<false><<<dim3((M / 128) * (H / 256)), 512, 0, stream>>>(abuf, wbuf, y, M, H, I);
}

// Round 11
// 952.330 us; speedup vs baseline: 1.3062x; 1.3062x over previous
//
#include <hip/hip_runtime.h>
#include <stdint.h>

typedef unsigned short u16;
typedef __attribute__((ext_vector_type(4))) float f32x4;
typedef __attribute__((ext_vector_type(8))) __bf16 bf16x8;
typedef __attribute__((ext_vector_type(8))) unsigned short u16x8;

__device__ __forceinline__ u16 f2bf(float f) {
  unsigned u = __builtin_bit_cast(unsigned, f);
  u = (u + 0x7fffu + ((u >> 16) & 1u)) >> 16;
  return (u16)u;
}

typedef __attribute__((address_space(1))) const void gvoid_t;
typedef __attribute__((address_space(3))) void lvoid_t;

__device__ __forceinline__ void gload_lds16(const void* g, void* l) {
  __builtin_amdgcn_global_load_lds((gvoid_t*)g, (lvoid_t*)l, 16, 0, 0);
}

// ---------------- dequant: w[row][k] = (q[row][k] - z[row][k/128]) * s[row][k/128], bf16
__global__ __launch_bounds__(256)
void dequant_kernel(const int* __restrict__ q, const float* __restrict__ s,
                    const int* __restrict__ z, u16* __restrict__ w, int K) {
  const int row = blockIdx.y;
  const int k = (blockIdx.x * 256 + threadIdx.x) << 3;
  const int ng = K >> 7;
  const int g = k >> 7;
  const float sv = s[(size_t)row * ng + g];
  const float zv = (float)z[(size_t)row * ng + g];
  const int4* qp = (const int4*)(q + (size_t)row * K + k);
  const int4 a = qp[0], b = qp[1];
  u16x8 o;
  o[0] = f2bf(((float)a.x - zv) * sv);
  o[1] = f2bf(((float)a.y - zv) * sv);
  o[2] = f2bf(((float)a.z - zv) * sv);
  o[3] = f2bf(((float)a.w - zv) * sv);
  o[4] = f2bf(((float)b.x - zv) * sv);
  o[5] = f2bf(((float)b.y - zv) * sv);
  o[6] = f2bf(((float)b.z - zv) * sv);
  o[7] = f2bf(((float)b.w - zv) * sv);
  *reinterpret_cast<u16x8*>(w + (size_t)row * K + k) = o;
}

// ---------------- fp32 -> bf16 bulk convert (x)
__global__ __launch_bounds__(256)
void cvt_kernel(const float* __restrict__ in, u16* __restrict__ out) {
  const size_t i = ((size_t)blockIdx.x * 256 + threadIdx.x) << 3;
  const float4* p = (const float4*)(in + i);
  const float4 a = p[0], b = p[1];
  u16x8 o;
  o[0] = f2bf(a.x); o[1] = f2bf(a.y); o[2] = f2bf(a.z); o[3] = f2bf(a.w);
  o[4] = f2bf(b.x); o[5] = f2bf(b.y); o[6] = f2bf(b.z); o[7] = f2bf(b.w);
  *reinterpret_cast<u16x8*>(out + i) = o;
}

// ---------------- 256x256 GEMM v9: sound counted-lgkm/vmcnt schedule
// C = A * B^T (bf16, K-major). 512 thr = 8 waves (2M x 4N); per-wave 128x64; BK=64.
// Tile T (buf p=T&1, other q): 4 phases, BARO at each phase start.
//   ph1: BARO; rd{b1,a1}; lgkm(0); stg A(T+1)h0->q; MFMA(a1,b1)
//        [ph2 reads issued post-MFMA1, order PINNED b2<a2<a4<a3 via sched_barrier(0)]
//   ph2: BARO; lgkm(8)[b2,a2 done; a4,a3 drain under MFMA]; stg A(T+1)h1->q; MFMA(a2,b1)
//   ph3: BARO; lgkm(4)[+a4]; stg B(T+2)h0->p; MFMA(a4,b2)
//   ph4: BARO; lgkm(0)[+a3]; stg B(T+2)h1->p; MFMA(a3,b2); GATE vmcnt(4)
// Soundness (all-waves): stage S issues only after a barrier following the wait
// that covers S's region's readers: A(T+1)->q.A read-drained T-1 ph4 lgkm(0) < BARO1;
// B(T+2)->p.B read-drained ph2 lgkm(8) < BARO3. Reads of tile T+1 issue after
// BARO1(T+1), which follows every wave's GATE (v8's missing barrier — the NaN race).
// GATE queue: B(T+1)[4] + A(T+1)[4] + B(T+2)[4] = 12 -> vmcnt(4) completes exactly
// next tile's inputs, leaves B(T+2) in flight (T4: never 0 in loop).
// Prologue: A(0),B(0)->buf0, B(1)->buf1; vmcnt(4) leaves B(1).
template<bool RELU2>
__global__ __launch_bounds__(512, 2)
void gemm256(const u16* __restrict__ Ap, const u16* __restrict__ Bp,
             void* __restrict__ Cptr, int M, int N, int K) {
  __shared__ __align__(16) u16 As[2][256][64];
  __shared__ __align__(16) u16 Bs[2][256][64];
  const int tid = threadIdx.x;
  const int lane = tid & 63;
  const int wid = tid >> 6;
  const int wr = wid >> 2, wc = wid & 3;

  const int nbx = N >> 8;
  const int nwg = gridDim.x;
  int bid = blockIdx.x;
  bid = (bid & 7) * (nwg >> 3) + (bid >> 3);   // XCD swizzle (nwg % 8 == 0)
  const int m0 = (bid / nbx) << 8;             // n-fastest (R6 order)
  const int n0 = (bid % nbx) << 8;

  const int srow = tid >> 3;        // staging row within 64-row sweep
  const int scol = tid & 7;         // staging 16B segment
  const int lr = lane & 15;
  const int lk = (lane >> 4) << 3;
  const int xorc = (lr & 7) << 3;   // read-side swizzle (row&7 == lr&7)

  // ds_read bases: row base per (array, buf); k byte-offset koff0 / koff0^64
  const char* baA0 = (const char*)&As[0][0][0] + (wr * 128 + lr) * 128;
  const char* baA1 = baA0 + 32768;
  const char* baB0 = (const char*)&Bs[0][0][0] + (wc * 64 + lr) * 128;
  const char* baB1 = baB0 + 32768;
  const int koff0 = (lk ^ xorc) * 2;

  f32x4 acc[8][4] = {};
  bf16x8 a1[4], a2[4], a3[4], a4[4], b1[4], b2[4];

  const int nk = K >> 6;

#define STG_A(bufi, h, kt) do { _Pragma("unroll") \
  for (int l_ = 0; l_ < 2; ++l_) { \
    const int r_ = (h) * 128 + l_ * 64 + srow; \
    gload_lds16(Ap + (size_t)(m0 + r_) * K + (size_t)((kt) << 6) + ((scol ^ (srow & 7)) << 3), \
                &As[bufi][r_][scol << 3]); } } while (0)
#define STG_B(bufi, h, kt) do { _Pragma("unroll") \
  for (int l_ = 0; l_ < 2; ++l_) { \
    const int r_ = (h) * 128 + l_ * 64 + srow; \
    gload_lds16(Bp + (size_t)(n0 + r_) * K + (size_t)((kt) << 6) + ((scol ^ (srow & 7)) << 3), \
                &Bs[bufi][r_][scol << 3]); } } while (0)
// base+imm reads: A rows (half*4+i)*16 -> imm (half*4+i)*2048; ks1 byte = koff0^64
#define RD_A(base, ks, half, dst) do { _Pragma("unroll") \
  for (int i_ = 0; i_ < 4; ++i_) \
    dst[i_] = *reinterpret_cast<const bf16x8*>( \
      (base) + ((half) * 4 + i_) * 2048 + (koff0 ^ ((ks) * 64))); } while (0)
#define RD_B(base, ks, dst) do { _Pragma("unroll") \
  for (int j_ = 0; j_ < 4; ++j_) \
    dst[j_] = *reinterpret_cast<const bf16x8*>( \
      (base) + j_ * 2048 + (koff0 ^ ((ks) * 64))); } while (0)
#define MFMA16(ASET, BSET, I0) do { _Pragma("unroll") \
  for (int i_ = 0; i_ < 4; ++i_) { _Pragma("unroll") \
    for (int j_ = 0; j_ < 4; ++j_) \
      acc[(I0) + i_][j_] = __builtin_amdgcn_mfma_f32_16x16x32_bf16( \
        ASET[i_], BSET[j_], acc[(I0) + i_][j_], 0, 0, 0); } } while (0)
#define BARO() do { asm volatile("" ::: "memory"); __builtin_amdgcn_s_barrier(); \
  asm volatile("" ::: "memory"); } while (0)
#define LGKM(n) do { asm volatile("s_waitcnt lgkmcnt(" #n ")" ::: "memory"); \
  __builtin_amdgcn_sched_barrier(0); } while (0)
#define SB0 __builtin_amdgcn_sched_barrier(0)
#define GATE4 asm volatile("s_waitcnt vmcnt(4)" ::: "memory")
#define PRIO(Q) do { __builtin_amdgcn_s_setprio(1); Q; __builtin_amdgcn_s_setprio(0); } while (0)
// One K-tile. bA/bB = read bases for buf p. SA1/SA2 = A(T+1) half stages (->q);
// SB3/SB4 = B(T+2) half stages (->p).
#define TILE4(bA, bB, SA1, SA2, SB3, SB4) do { \
  BARO(); \
  RD_B(bB, 0, b1); RD_A(bA, 0, 0, a1); \
  LGKM(0); \
  SA1; \
  PRIO(MFMA16(a1, b1, 0)); \
  SB0; RD_B(bB, 1, b2); SB0; RD_A(bA, 0, 1, a2); SB0; RD_A(bA, 1, 1, a4); SB0; RD_A(bA, 1, 0, a3); \
  BARO(); \
  LGKM(8); \
  SA2; \
  PRIO(MFMA16(a2, b1, 4)); \
  BARO(); \
  LGKM(4); \
  SB3; \
  PRIO(MFMA16(a4, b2, 4)); \
  BARO(); \
  LGKM(0); \
  SB4; \
  PRIO(MFMA16(a3, b2, 0)); \
  GATE4; \
} while (0)

  // prologue: A(0),B(0)->buf0, B(1)->buf1 (12 loads); vmcnt(4) leaves B(1) in flight
  STG_A(0, 0, 0); STG_A(0, 1, 0);
  STG_B(0, 0, 0); STG_B(0, 1, 0);
  STG_B(1, 0, 1); STG_B(1, 1, 1);
  asm volatile("s_waitcnt vmcnt(4)" ::: "memory");

  const int nit = nk >> 1;
  for (int it = 0; it < nit; ++it) {
    const int t1 = 2 * it + 1;
    int t2 = 2 * it + 2; if (t2 >= nk) t2 -= nk;   // wrap: tail stages are dummies
    int t3 = 2 * it + 3; if (t3 >= nk) t3 -= nk;
    // tile 2it (buf0): stage A(t1)->buf1, B(t2)->buf0
    TILE4(baA0, baB0, STG_A(1, 0, t1), STG_A(1, 1, t1), STG_B(0, 0, t2), STG_B(0, 1, t2));
    // tile t1 (buf1): stage A(t2)->buf0, B(t3)->buf1
    TILE4(baA1, baB1, STG_A(0, 0, t2), STG_A(0, 1, t2), STG_B(1, 0, t3), STG_B(1, 1, t3));
  }
  asm volatile("s_waitcnt vmcnt(0)" ::: "memory");  // drain dummy stages before epilogue

  // epilogue: C/D layout col = lane&15, row = (lane>>4)*4 + reg  [m89-verified]
  const int crow = (lane >> 4) << 2;
  const int ccol = lane & 15;
#pragma unroll
  for (int i = 0; i < 8; ++i) {
#pragma unroll
    for (int j = 0; j < 4; ++j) {
#pragma unroll
      for (int q = 0; q < 4; ++q) {
        const int m = m0 + wr * 128 + i * 16 + crow + q;
        const int n = n0 + wc * 64 + j * 16 + ccol;
        const float v = acc[i][j][q];
        if constexpr (RELU2) {
          const float r = fmaxf(v, 0.f);
          ((u16*)Cptr)[(size_t)m * N + n] = f2bf(r * r);
        } else {
          ((float*)Cptr)[(size_t)m * N + n] = v;
        }
      }
    }
  }
#undef STG_A
#undef STG_B
#undef RD_A
#undef RD_B
#undef MFMA16
#undef BARO
#undef LGKM
#undef SB0
#undef GATE4
#undef PRIO
#undef TILE4
}

extern "C" void kernel_launch(void* const* d_in, const int* in_sizes, int n_in,
                              void* d_out, int out_size, void* d_ws, size_t ws_size,
                              hipStream_t stream) {
  const float* x    = (const float*)d_in[0];
  const int*   q_up = (const int*)d_in[1];
  const float* s_up = (const float*)d_in[2];
  const int*   z_up = (const int*)d_in[3];
  const int*   q_dn = (const int*)d_in[4];
  const float* s_dn = (const float*)d_in[5];
  const int*   z_dn = (const int*)d_in[6];
  float* y = (float*)d_out;

  const int H = 4096, I = 14336;
  const int M = in_sizes[0] / H;  // 4096 tokens

  const size_t wbytes = (size_t)I * H * 2;   // 117.4 MB bf16 weight buffer (reused)
  const size_t abytes = (size_t)M * I * 2;   // 117.4 MB bf16 activations
  const size_t xbytes = (size_t)M * H * 2;   // 33.5 MB bf16 x
  u16* wbuf = (u16*)d_ws;
  u16* abuf = (u16*)((char*)d_ws + wbytes);
  u16* xbf  = (u16*)((char*)d_ws + wbytes + abytes);
  if (ws_size < wbytes + abytes + xbytes) return;  // insufficient scratch: fail cleanly

  // 1. dequant W_up [I, H] -> bf16
  dequant_kernel<<<dim3(H / 8 / 256, I), 256, 0, stream>>>(q_up, s_up, z_up, wbuf, H);
  // 1b. x -> bf16
  cvt_kernel<<<dim3((int)(((size_t)M * H) >> 11)), 256, 0, stream>>>(x, xbf);
  // 2. a = relu(x @ W_up^T)^2, bf16   (grid 896 % 8 == 0)
  gemm256<true><<<dim3((M / 256) * (I / 256)), 512, 0, stream>>>(xbf, wbuf, abuf, M, I, H);
  // 3. dequant W_down [H, I] -> bf16
  dequant_kernel<<<dim3(I / 8 / 256, H), 256, 0, stream>>>(q_dn, s_dn, z_dn, wbuf, I);
  // 4. y = a @ W_down^T, fp32   (grid 256 % 8 == 0)
  gemm256<false><<<dim3((M / 256) * (H / 256)), 512, 0, stream>>>(abuf, wbuf, y, M, H, I);
}